// Round 4
// baseline (695.261 us; speedup 1.0000x reference)
//
#include <hip/hip_runtime.h>
#include <hip/hip_bf16.h>

#define N_NODES 100000
#define N_EDGES 1600000
#define IN_F 512
#define HID 128
#define OUT_F 32
#define ALPHA 0.01f
#define K_STEPS 10

// bucketed CSR build params
#define NB 256          // phase-1 blocks
#define CH 6250         // edges per phase-1 block (NB*CH == N_EDGES exactly)
#define NBUCK 391       // buckets of 256 rows: ceil(100000/256)
#define NS (NBUCK * NB) // scan size = 100096
#define CAP 5120        // LDS stage capacity per bucket

typedef __attribute__((ext_vector_type(8))) short short8;
typedef __attribute__((ext_vector_type(4))) float f32x4;
typedef __attribute__((ext_vector_type(8))) _Float16 half8;

__device__ __forceinline__ unsigned short f2bf(float f) {
    union { float f; unsigned u; } c; c.f = f;
    unsigned r = c.u + 0x7FFF + ((c.u >> 16) & 1);   // RNE
    return (unsigned short)(r >> 16);
}

// ============================ CSR build: phase 1 (bucket histogram) ============================

__launch_bounds__(256)
__global__ void p1_hist_kernel(const int* __restrict__ er, int* __restrict__ S) {
    __shared__ int h[NBUCK];
    int t = threadIdx.x, bl = blockIdx.x;
    for (int b = t; b < NBUCK; b += 256) h[b] = 0;
    __syncthreads();
    int s = bl * CH, e = s + CH;
    for (int i = s + t; i < e; i += 256) atomicAdd(&h[er[i] >> 8], 1);
    __syncthreads();
    for (int b = t; b < NBUCK; b += 256) S[b * NB + bl] = h[b];
}

// ============================ generic exclusive scan (3 kernels) ============================

#define SCAN_B 512
__global__ void scan_block_kernel(const int* __restrict__ cnt, int* __restrict__ partial,
                                  int* __restrict__ bsum, int n) {
    __shared__ int s[SCAN_B];
    int tid = threadIdx.x;
    int i = blockIdx.x * SCAN_B + tid;
    int v = (i < n) ? cnt[i] : 0;
    s[tid] = v;
    __syncthreads();
    for (int off = 1; off < SCAN_B; off <<= 1) {
        int t = (tid >= off) ? s[tid - off] : 0;
        __syncthreads();
        s[tid] += t;
        __syncthreads();
    }
    if (i < n) partial[i] = s[tid];
    if (tid == SCAN_B - 1) bsum[blockIdx.x] = s[tid];
}

__global__ void scan_tops_kernel(int* __restrict__ bsum, int nb) {
    __shared__ int s[256];
    int t = threadIdx.x;
    int v = (t < nb) ? bsum[t] : 0;
    s[t] = v;
    __syncthreads();
    for (int off = 1; off < 256; off <<= 1) {
        int x = (t >= off) ? s[t - off] : 0;
        __syncthreads();
        s[t] += x;
        __syncthreads();
    }
    if (t < nb) bsum[t] = s[t] - v;   // exclusive
}

__global__ void scan_finish_excl_kernel(const int* __restrict__ partial, const int* __restrict__ bsum,
                                        const int* __restrict__ cnt, int* __restrict__ excl, int n) {
    int i = blockIdx.x * blockDim.x + threadIdx.x;
    if (i < n) excl[i] = partial[i] + bsum[i / SCAN_B] - cnt[i];
}

// ============================ CSR build: phase 1 scatter (by bucket) ============================

__launch_bounds__(256)
__global__ void p1_scatter_kernel(const int* __restrict__ er, const int* __restrict__ ec,
                                  const float* __restrict__ ev, const int* __restrict__ Sexcl,
                                  int2* __restrict__ sorted) {
    __shared__ int cur[NBUCK];
    int t = threadIdx.x, bl = blockIdx.x;
    for (int b = t; b < NBUCK; b += 256) cur[b] = Sexcl[b * NB + bl];
    __syncthreads();
    int s = bl * CH, e = s + CH;
    for (int i = s + t; i < e; i += 256) {
        int r = er[i];
        int b = r >> 8;
        int pos = atomicAdd(&cur[b], 1);
        sorted[pos] = make_int2(ec[i] | ((r & 255) << 17), __float_as_int(ev[i]));
    }
}

// ============================ CSR build: phase 2 (sort within bucket, in LDS) ============================

__launch_bounds__(256)
__global__ void p2_build_kernel(const int2* __restrict__ sorted, const int* __restrict__ Sexcl,
                                int* __restrict__ rowptr, int2* __restrict__ edges) {
    __shared__ int rcnt[256], rexcl[256], rcur[256], sc[256];
    __shared__ int2 stage[CAP];
    int t = threadIdx.x, b = blockIdx.x;
    int base = Sexcl[b * NB];
    int end = (b == NBUCK - 1) ? N_EDGES : Sexcl[(b + 1) * NB];
    int cnt = end - base;
    rcnt[t] = 0; rcur[t] = 0;
    __syncthreads();
    for (int i = t; i < cnt; i += 256)
        atomicAdd(&rcnt[((unsigned)sorted[base + i].x) >> 17], 1);
    __syncthreads();
    int v = rcnt[t];
    sc[t] = v;
    __syncthreads();
    for (int off = 1; off < 256; off <<= 1) {
        int x = (t >= off) ? sc[t - off] : 0;
        __syncthreads();
        sc[t] += x;
        __syncthreads();
    }
    rexcl[t] = sc[t] - v;
    int row = (b << 8) + t;
    if (row < N_NODES) rowptr[row] = base + sc[t] - v;
    if (b == NBUCK - 1 && t == 0) rowptr[N_NODES] = N_EDGES;
    __syncthreads();
    for (int i = t; i < cnt; i += 256) {
        int2 ed = sorted[base + i];
        int lr = ((unsigned)ed.x) >> 17;
        int2 o = make_int2(ed.x & 0x1FFFF, ed.y);
        int pos = rexcl[lr] + atomicAdd(&rcur[lr], 1);
        if (pos < CAP) stage[pos] = o;
        else edges[base + pos] = o;   // overflow fallback (statistically never)
    }
    __syncthreads();
    int lim = cnt < CAP ? cnt : CAP;
    for (int i = t; i < lim; i += 256) edges[base + i] = stage[i];
}

// ============================ degree-sorted row schedule ============================
// rowinfo[i] = { start, perm | (deg<<17) }, i in degree-sorted order.

#define DCLASS 256

__launch_bounds__(256)
__global__ void deg_hist_kernel(const int* __restrict__ rowptr, int* __restrict__ gh) {
    __shared__ int h[DCLASS];
    int t = threadIdx.x;
    h[t] = 0;
    __syncthreads();
    int i = blockIdx.x * 256 + t;
    if (i < N_NODES) {
        int d = rowptr[i + 1] - rowptr[i];
        if (d > 255) d = 255;
        atomicAdd(&h[d], 1);
    }
    __syncthreads();
    if (h[t]) atomicAdd(&gh[t], h[t]);
}

__global__ void deg_scan_kernel(int* __restrict__ gh) {
    __shared__ int s[DCLASS];
    int t = threadIdx.x;
    int v = gh[t];
    s[t] = v;
    __syncthreads();
    for (int off = 1; off < 256; off <<= 1) {
        int x = (t >= off) ? s[t - off] : 0;
        __syncthreads();
        s[t] += x;
        __syncthreads();
    }
    gh[t] = s[t] - v;   // exclusive base
}

__launch_bounds__(256)
__global__ void deg_scatter_kernel(const int* __restrict__ rowptr, const int* __restrict__ gbase,
                                   int* __restrict__ gcur, int2* __restrict__ rowinfo) {
    __shared__ int lcnt[DCLASS], lbase[DCLASS], lcur[DCLASS];
    int t = threadIdx.x;
    lcnt[t] = 0; lcur[t] = 0;
    __syncthreads();
    int i = blockIdx.x * 256 + t;
    int d = 0, s = 0, dc = 0;
    bool valid = i < N_NODES;
    if (valid) {
        s = rowptr[i];
        d = rowptr[i + 1] - s;
        dc = d > 255 ? 255 : d;
        atomicAdd(&lcnt[dc], 1);
    }
    __syncthreads();
    if (lcnt[t]) lbase[t] = gbase[t] + atomicAdd(&gcur[t], lcnt[t]);
    __syncthreads();
    if (valid) {
        int pos = lbase[dc] + atomicAdd(&lcur[dc], 1);
        rowinfo[pos] = make_int2(s, i | (d << 17));
    }
}

// ============================ weight pre-convert ============================

__global__ void wconv_kernel(const float* __restrict__ W1, const float* __restrict__ W2,
                             short* __restrict__ W1T, short* __restrict__ W2T) {
    int idx = blockIdx.x * 256 + threadIdx.x;
    if (idx < IN_F * HID) {
        int k = idx >> 7, nn = idx & 127;
        W1T[nn * IN_F + k] = (short)f2bf(W1[idx]);
    }
    if (idx < HID * OUT_F) {
        int k = idx >> 5, nn = idx & 31;
        W2T[nn * HID + k] = (short)f2bf(W2[idx]);
    }
}

// ============================ fused MLP (bf16 MFMA), fp16 output ============================

#define AB_PITCH 40
#define H1_PITCH 136

__launch_bounds__(256)
__global__ void mlp_kernel(const float* __restrict__ X, const short* __restrict__ W1T,
                           const float* __restrict__ b1, const short* __restrict__ W2T,
                           const float* __restrict__ b2, _Float16* __restrict__ H, int M) {
    __shared__ char lds[43520];
    short* As  = (short*)lds;
    short* Bs  = (short*)(lds + 10240);
    short* H1s = (short*)lds;
    short* W2s = (short*)(lds + 34816);

    const int t = threadIdx.x;
    const int m0 = blockIdx.x * 128;
    const int l = t & 63;
    const int w = t >> 6;
    const int l15 = l & 15;
    const int koff = (l >> 4) << 3;

    {
        int nn = t >> 3, seg = (t & 7) << 4;
        const short8* src = (const short8*)(W2T + nn * HID + seg);
        *(short8*)&W2s[nn * H1_PITCH + seg] = src[0];
        *(short8*)&W2s[nn * H1_PITCH + seg + 8] = src[1];
    }

    const int arow = t >> 1;
    const int ah = (t & 1) << 4;
    int gm = m0 + arow; if (gm >= M) gm = M - 1;
    const float* xrow = X + (size_t)gm * IN_F;
    const short* wrow = W1T + (size_t)arow * IN_F;

    f32x4 acc[2][8];
    #pragma unroll
    for (int m = 0; m < 2; ++m)
        #pragma unroll
        for (int n = 0; n < 8; ++n) acc[m][n] = (f32x4){0.f, 0.f, 0.f, 0.f};

    for (int k0 = 0; k0 < IN_F; k0 += 32) {
        float4 v0 = *(const float4*)(xrow + k0 + ah);
        float4 v1 = *(const float4*)(xrow + k0 + ah + 4);
        float4 v2 = *(const float4*)(xrow + k0 + ah + 8);
        float4 v3 = *(const float4*)(xrow + k0 + ah + 12);
        short8 p0, p1;
        p0[0] = f2bf(v0.x); p0[1] = f2bf(v0.y); p0[2] = f2bf(v0.z); p0[3] = f2bf(v0.w);
        p0[4] = f2bf(v1.x); p0[5] = f2bf(v1.y); p0[6] = f2bf(v1.z); p0[7] = f2bf(v1.w);
        p1[0] = f2bf(v2.x); p1[1] = f2bf(v2.y); p1[2] = f2bf(v2.z); p1[3] = f2bf(v2.w);
        p1[4] = f2bf(v3.x); p1[5] = f2bf(v3.y); p1[6] = f2bf(v3.z); p1[7] = f2bf(v3.w);
        short8 q0 = *(const short8*)(wrow + k0 + ah);
        short8 q1 = *(const short8*)(wrow + k0 + ah + 8);
        __syncthreads();
        *(short8*)&As[arow * AB_PITCH + ah] = p0;
        *(short8*)&As[arow * AB_PITCH + ah + 8] = p1;
        *(short8*)&Bs[arow * AB_PITCH + ah] = q0;
        *(short8*)&Bs[arow * AB_PITCH + ah + 8] = q1;
        __syncthreads();
        short8 af0 = *(const short8*)&As[(32 * w + l15) * AB_PITCH + koff];
        short8 af1 = *(const short8*)&As[(32 * w + 16 + l15) * AB_PITCH + koff];
        #pragma unroll
        for (int n = 0; n < 8; ++n) {
            short8 bf = *(const short8*)&Bs[(16 * n + l15) * AB_PITCH + koff];
            acc[0][n] = __builtin_amdgcn_mfma_f32_16x16x32_bf16(af0, bf, acc[0][n], 0, 0, 0);
            acc[1][n] = __builtin_amdgcn_mfma_f32_16x16x32_bf16(af1, bf, acc[1][n], 0, 0, 0);
        }
    }

    float bcol[8];
    #pragma unroll
    for (int n = 0; n < 8; ++n) bcol[n] = b1[16 * n + l15];
    __syncthreads();
    #pragma unroll
    for (int m = 0; m < 2; ++m)
        #pragma unroll
        for (int n = 0; n < 8; ++n)
            #pragma unroll
            for (int reg = 0; reg < 4; ++reg) {
                int hrow = 32 * w + 16 * m + ((l >> 4) << 2) + reg;
                float v = fmaxf(acc[m][n][reg] + bcol[n], 0.f);
                H1s[hrow * H1_PITCH + 16 * n + l15] = (short)f2bf(v);
            }
    __syncthreads();

    f32x4 acc2[2][2];
    #pragma unroll
    for (int m = 0; m < 2; ++m)
        #pragma unroll
        for (int n = 0; n < 2; ++n) acc2[m][n] = (f32x4){0.f, 0.f, 0.f, 0.f};
    #pragma unroll
    for (int kc = 0; kc < 4; ++kc) {
        short8 a0 = *(const short8*)&H1s[(32 * w + l15) * H1_PITCH + (kc << 5) + koff];
        short8 a1 = *(const short8*)&H1s[(32 * w + 16 + l15) * H1_PITCH + (kc << 5) + koff];
        #pragma unroll
        for (int n = 0; n < 2; ++n) {
            short8 bf = *(const short8*)&W2s[(16 * n + l15) * H1_PITCH + (kc << 5) + koff];
            acc2[0][n] = __builtin_amdgcn_mfma_f32_16x16x32_bf16(a0, bf, acc2[0][n], 0, 0, 0);
            acc2[1][n] = __builtin_amdgcn_mfma_f32_16x16x32_bf16(a1, bf, acc2[1][n], 0, 0, 0);
        }
    }
    #pragma unroll
    for (int n = 0; n < 2; ++n) {
        float bc = b2[16 * n + l15];
        #pragma unroll
        for (int m = 0; m < 2; ++m)
            #pragma unroll
            for (int reg = 0; reg < 4; ++reg) {
                int row = 32 * w + 16 * m + ((l >> 4) << 2) + reg;
                int g = m0 + row;
                if (g < M)
                    H[(size_t)g * OUT_F + 16 * n + l15] = (_Float16)fmaxf(acc2[m][n][reg] + bc, 0.f);
            }
    }
}

// ============================ SpMM step (fp16 rows, 4 lanes/row, degree-sorted) ============================

template <int LAST>
__launch_bounds__(256)
__global__ void spmm_kernel(const int2* __restrict__ rowinfo, const int2* __restrict__ edges,
                            const half8* __restrict__ src, half8* __restrict__ dst,
                            float* __restrict__ dstf, int n) {
    int g = blockIdx.x * 256 + threadIdx.x;
    int r = g >> 2, lane = g & 3;
    if (r >= n) return;
    int2 info = rowinfo[r];
    int s = info.x;
    int row = info.y & 0x1FFFF;
    int e = s + (((unsigned)info.y) >> 17);
    float a0 = 0.f, a1 = 0.f, a2 = 0.f, a3 = 0.f, a4 = 0.f, a5 = 0.f, a6 = 0.f, a7 = 0.f;
    int i = s;
    for (; i + 4 <= e; i += 4) {
        int2 e0 = edges[i], e1 = edges[i + 1], e2 = edges[i + 2], e3 = edges[i + 3];
        half8 v0 = src[(size_t)e0.x * 4 + lane];
        half8 v1 = src[(size_t)e1.x * 4 + lane];
        half8 v2 = src[(size_t)e2.x * 4 + lane];
        half8 v3 = src[(size_t)e3.x * 4 + lane];
        float w0 = __int_as_float(e0.y), w1 = __int_as_float(e1.y);
        float w2 = __int_as_float(e2.y), w3 = __int_as_float(e3.y);
        a0 = fmaf(w0, (float)v0[0], a0); a1 = fmaf(w0, (float)v0[1], a1);
        a2 = fmaf(w0, (float)v0[2], a2); a3 = fmaf(w0, (float)v0[3], a3);
        a4 = fmaf(w0, (float)v0[4], a4); a5 = fmaf(w0, (float)v0[5], a5);
        a6 = fmaf(w0, (float)v0[6], a6); a7 = fmaf(w0, (float)v0[7], a7);
        a0 = fmaf(w1, (float)v1[0], a0); a1 = fmaf(w1, (float)v1[1], a1);
        a2 = fmaf(w1, (float)v1[2], a2); a3 = fmaf(w1, (float)v1[3], a3);
        a4 = fmaf(w1, (float)v1[4], a4); a5 = fmaf(w1, (float)v1[5], a5);
        a6 = fmaf(w1, (float)v1[6], a6); a7 = fmaf(w1, (float)v1[7], a7);
        a0 = fmaf(w2, (float)v2[0], a0); a1 = fmaf(w2, (float)v2[1], a1);
        a2 = fmaf(w2, (float)v2[2], a2); a3 = fmaf(w2, (float)v2[3], a3);
        a4 = fmaf(w2, (float)v2[4], a4); a5 = fmaf(w2, (float)v2[5], a5);
        a6 = fmaf(w2, (float)v2[6], a6); a7 = fmaf(w2, (float)v2[7], a7);
        a0 = fmaf(w3, (float)v3[0], a0); a1 = fmaf(w3, (float)v3[1], a1);
        a2 = fmaf(w3, (float)v3[2], a2); a3 = fmaf(w3, (float)v3[3], a3);
        a4 = fmaf(w3, (float)v3[4], a4); a5 = fmaf(w3, (float)v3[5], a5);
        a6 = fmaf(w3, (float)v3[6], a6); a7 = fmaf(w3, (float)v3[7], a7);
    }
    for (; i < e; ++i) {
        int2 e0 = edges[i];
        half8 v0 = src[(size_t)e0.x * 4 + lane];
        float w0 = __int_as_float(e0.y);
        a0 = fmaf(w0, (float)v0[0], a0); a1 = fmaf(w0, (float)v0[1], a1);
        a2 = fmaf(w0, (float)v0[2], a2); a3 = fmaf(w0, (float)v0[3], a3);
        a4 = fmaf(w0, (float)v0[4], a4); a5 = fmaf(w0, (float)v0[5], a5);
        a6 = fmaf(w0, (float)v0[6], a6); a7 = fmaf(w0, (float)v0[7], a7);
    }
    half8 self = src[(size_t)row * 4 + lane];
    float r0 = (1.f - ALPHA) * a0 + ALPHA * (float)self[0];
    float r1 = (1.f - ALPHA) * a1 + ALPHA * (float)self[1];
    float r2 = (1.f - ALPHA) * a2 + ALPHA * (float)self[2];
    float r3 = (1.f - ALPHA) * a3 + ALPHA * (float)self[3];
    float r4 = (1.f - ALPHA) * a4 + ALPHA * (float)self[4];
    float r5 = (1.f - ALPHA) * a5 + ALPHA * (float)self[5];
    float r6 = (1.f - ALPHA) * a6 + ALPHA * (float)self[6];
    float r7 = (1.f - ALPHA) * a7 + ALPHA * (float)self[7];
    if (LAST) {
        float* o = dstf + (size_t)row * OUT_F + lane * 8;
        *(float4*)o = make_float4(r0, r1, r2, r3);
        *(float4*)(o + 4) = make_float4(r4, r5, r6, r7);
    } else {
        half8 o;
        o[0] = (_Float16)r0; o[1] = (_Float16)r1; o[2] = (_Float16)r2; o[3] = (_Float16)r3;
        o[4] = (_Float16)r4; o[5] = (_Float16)r5; o[6] = (_Float16)r6; o[7] = (_Float16)r7;
        dst[(size_t)row * 4 + lane] = o;
    }
}

// ============================ launch ============================

extern "C" void kernel_launch(void* const* d_in, const int* in_sizes, int n_in,
                              void* d_out, int out_size, void* d_ws, size_t ws_size,
                              hipStream_t stream) {
    const float* x  = (const float*)d_in[0];
    const int*   er = (const int*)d_in[1];
    const int*   ec = (const int*)d_in[2];
    const float* ev = (const float*)d_in[3];
    const float* W1 = (const float*)d_in[4];
    const float* b1 = (const float*)d_in[5];
    const float* W2 = (const float*)d_in[6];
    const float* b2 = (const float*)d_in[7];
    float* out = (float*)d_out;

    char* ws = (char*)d_ws;
    _Float16* bufA  = (_Float16*)(ws + 0);         // 6,400,000
    _Float16* bufB  = (_Float16*)(ws + 6400000);   // 6,400,000
    int2*  edges   = (int2*) (ws + 12800000);      // 12,800,000
    int2*  sorted  = (int2*) (ws + 25600000);      // 12,800,000
    short* W1T     = (short*)(ws + 38400000);      // 131,072
    short* W2T     = (short*)(ws + 38531072);      // 8,192
    int*   rowptr  = (int*)  (ws + 38539264);      // 400,016
    int*   S       = (int*)  (ws + 38939280);      // 400,384
    int*   Spart   = (int*)  (ws + 39339664);      // 400,384
    int*   Sexcl   = (int*)  (ws + 39740048);      // 400,384
    int*   bsum    = (int*)  (ws + 40140432);      // 1,024
    int2*  rowinfo = (int2*) (ws + 40141456);      // 800,000
    int*   gh      = (int*)  (ws + 40941456);      // 1,024 (deg class bases)
    int*   gcur    = (int*)  (ws + 40942480);      // 1,024 (deg class cursors)

    // ---- CSR build (bucketed, no global atomics) ----
    p1_hist_kernel<<<NB, 256, 0, stream>>>(er, S);
    int nb = (NS + SCAN_B - 1) / SCAN_B;  // 196
    scan_block_kernel<<<nb, SCAN_B, 0, stream>>>(S, Spart, bsum, NS);
    scan_tops_kernel<<<1, 256, 0, stream>>>(bsum, nb);
    scan_finish_excl_kernel<<<(NS + 255) / 256, 256, 0, stream>>>(Spart, bsum, S, Sexcl, NS);
    p1_scatter_kernel<<<NB, 256, 0, stream>>>(er, ec, ev, Sexcl, sorted);
    p2_build_kernel<<<NBUCK, 256, 0, stream>>>(sorted, Sexcl, rowptr, edges);

    // ---- degree-sorted row schedule ----
    hipMemsetAsync(gh, 0, 2048, stream);   // zeroes gh + gcur (contiguous)
    deg_hist_kernel<<<NBUCK, 256, 0, stream>>>(rowptr, gh);
    deg_scan_kernel<<<1, 256, 0, stream>>>(gh);
    deg_scatter_kernel<<<NBUCK, 256, 0, stream>>>(rowptr, gh, gcur, rowinfo);

    // ---- weights to bf16 (transposed) ----
    wconv_kernel<<<(IN_F * HID + 255) / 256, 256, 0, stream>>>(W1, W2, W1T, W2T);

    // ---- fused MLP ----
    mlp_kernel<<<(N_NODES + 127) / 128, 256, 0, stream>>>(x, W1T, b1, W2T, b2, bufA, N_NODES);

    // ---- propagation (fp16, degree-sorted schedule) ----
    _Float16* src = bufA;
    for (int step = 0; step < K_STEPS; ++step) {
        _Float16* dst = (step & 1) ? bufA : bufB;
        int grid = (N_NODES * 4 + 255) / 256;
        if (step == K_STEPS - 1)
            spmm_kernel<1><<<grid, 256, 0, stream>>>(rowinfo, edges, (const half8*)src,
                                                     (half8*)dst, out, N_NODES);
        else
            spmm_kernel<0><<<grid, 256, 0, stream>>>(rowinfo, edges, (const half8*)src,
                                                     (half8*)dst, nullptr, N_NODES);
        src = dst;
    }
}